// Round 1
// baseline (662.560 us; speedup 1.0000x reference)
//
#include <hip/hip_runtime.h>

#define IDIM 180
#define SDIM 1536
#define NB   8
#define NI   8192
#define NS   64

typedef short bf16x8 __attribute__((ext_vector_type(8)));
typedef float f32x4  __attribute__((ext_vector_type(4)));

__device__ __forceinline__ short f2bf(float x){
  union { float f; unsigned u; } v; v.f = x;
  unsigned r = v.u + 0x7fffu + ((v.u >> 16) & 1u);   // RNE
  return (short)(r >> 16);
}

__device__ __forceinline__ bf16x8 cvt8(const float* p){
  const float4* p4 = (const float4*)p;
  float4 a = p4[0], b = p4[1];
  bf16x8 r;
  r[0]=f2bf(a.x); r[1]=f2bf(a.y); r[2]=f2bf(a.z); r[3]=f2bf(a.w);
  r[4]=f2bf(b.x); r[5]=f2bf(b.y); r[6]=f2bf(b.z); r[7]=f2bf(b.w);
  return r;
}

// ---- Kernel A: slot -> bf16 row-major copy + bf16 transpose (slotT[b][d][s]) ----
__global__ __launch_bounds__(256) void kA(const float* __restrict__ slot,
                                          short* __restrict__ slot_bf,
                                          short* __restrict__ slotT){
  int i = blockIdx.x * 256 + threadIdx.x;          // < 8*64*1536
  float v = slot[i];
  short h = f2bf(v);
  slot_bf[i] = h;
  int d  = i % SDIM;
  int bs = i / SDIM;
  int b  = bs >> 6, s = bs & 63;
  slotT[((b * SDIM + d) << 6) + s] = h;
}

// ---- Kernel B: A[e][c] = sum_d Wq[e][d] * Wk[c][d], stored bf16, 192 rows (>=180 zero) ----
__global__ __launch_bounds__(256) void kB(const float* __restrict__ Wq,
                                          const float* __restrict__ Wk,
                                          short* __restrict__ Abf){
  int tn = blockIdx.x;                              // 0..95 -> c-tile
  int t = threadIdx.x, w = t >> 6, l = t & 63;
  int l15 = l & 15, q = l >> 4;
  int cc = tn * 16 + l15;                           // column c (row of Wk)
  const float* wkrow = Wk + (size_t)cc * SDIM;
  f32x4 acc[3];
  #pragma unroll
  for (int tt = 0; tt < 3; ++tt) acc[tt] = (f32x4){0.f,0.f,0.f,0.f};
  for (int ks = 0; ks < 48; ++ks){
    int d0 = ks * 32 + q * 8;
    bf16x8 bfrag = cvt8(wkrow + d0);
    #pragma unroll
    for (int tt = 0; tt < 3; ++tt){
      int e = (w + 4*tt) * 16 + l15;
      bf16x8 afrag = {0,0,0,0,0,0,0,0};
      if (e < IDIM) afrag = cvt8(Wq + (size_t)e * SDIM + d0);
      acc[tt] = __builtin_amdgcn_mfma_f32_16x16x32_bf16(afrag, bfrag, acc[tt], 0, 0, 0);
    }
  }
  #pragma unroll
  for (int tt = 0; tt < 3; ++tt){
    int tm = w + 4*tt;
    #pragma unroll
    for (int r = 0; r < 4; ++r){
      int e = tm * 16 + q * 4 + r;                  // rows >=180 naturally 0
      Abf[(size_t)e * SDIM + cc] = f2bf(acc[tt][r]);
    }
  }
}

// ---- Kernel C: MT[b][s][e] = sum_c A[e][c]*slot[b][s][c]  (bf16, e padded to 192) ----
__global__ __launch_bounds__(256) void kC(const short* __restrict__ Abf,
                                          const short* __restrict__ slot_bf,
                                          short* __restrict__ MT){
  int b = blockIdx.x >> 2, tn = blockIdx.x & 3;
  int t = threadIdx.x, w = t >> 6, l = t & 63;
  int l15 = l & 15, q = l >> 4;
  int s = tn * 16 + l15;
  const short* srow = slot_bf + (size_t)(b * NS + s) * SDIM;
  f32x4 acc[3];
  #pragma unroll
  for (int tt = 0; tt < 3; ++tt) acc[tt] = (f32x4){0.f,0.f,0.f,0.f};
  for (int ks = 0; ks < 48; ++ks){
    int c0 = ks * 32 + q * 8;
    bf16x8 bfrag = *(const bf16x8*)(srow + c0);
    #pragma unroll
    for (int tt = 0; tt < 3; ++tt){
      int e = (w + 4*tt) * 16 + l15;
      bf16x8 afrag = *(const bf16x8*)(Abf + (size_t)e * SDIM + c0);
      acc[tt] = __builtin_amdgcn_mfma_f32_16x16x32_bf16(afrag, bfrag, acc[tt], 0, 0, 0);
    }
  }
  #pragma unroll
  for (int tt = 0; tt < 3; ++tt){
    #pragma unroll
    for (int r = 0; r < 4; ++r){
      int e = (w + 4*tt) * 16 + q * 4 + r;
      MT[(size_t)(b * NS + s) * 192 + e] = f2bf(acc[tt][r]);
    }
  }
}

// ---- Kernel D: fused LN1 -> dots -> softmax -> w@slot -> LN2 ----
// block = 256 thr (4 waves), 16 rows per block; wave w owns 384 output cols.
__global__ __launch_bounds__(256) void kD(const float* __restrict__ x,
                                          const short* __restrict__ slotT,
                                          const short* __restrict__ MT,
                                          const float* __restrict__ g1,
                                          const float* __restrict__ b1,
                                          const float* __restrict__ g2,
                                          const float* __restrict__ b2,
                                          float* __restrict__ outS,
                                          float* __restrict__ outW){
  __shared__ __align__(16) float xs[16 * IDIM];
  __shared__ __align__(16) short xnbf[16 * 192];
  __shared__ __align__(16) float dotsS[16 * 68];
  __shared__ __align__(16) short wbf[16 * 80];
  __shared__ float stats[4][16][2];
  __shared__ float smu[16], srstd[16];

  int t = threadIdx.x;
  int blk = blockIdx.x;
  int b = blk >> 9;
  int i0 = (blk & 511) << 4;
  const float* xp = x + (size_t)(b * NI + i0) * IDIM;

  { // stage x tile (2880 contiguous floats, 16B aligned)
    const float4* src = (const float4*)xp;
    float4* dst = (float4*)xs;
    for (int idx = t; idx < 720; idx += 256) dst[idx] = src[idx];
  }
  __syncthreads();

  { // layernorm over 180, write bf16 zero-padded to 192
    int row = t >> 4, j16 = t & 15;
    float vals[12];
    float sum = 0.f, sq = 0.f;
    #pragma unroll
    for (int k = 0; k < 12; ++k){
      int e = j16 + 16 * k;
      float v = (e < IDIM) ? xs[row * IDIM + e] : 0.f;
      vals[k] = v; sum += v; sq += v * v;
    }
    #pragma unroll
    for (int m = 1; m < 16; m <<= 1){ sum += __shfl_xor(sum, m); sq += __shfl_xor(sq, m); }
    float mu  = sum * (1.f / IDIM);
    float var = sq * (1.f / IDIM) - mu * mu;
    float rstd = rsqrtf(var + 1e-5f);
    #pragma unroll
    for (int k = 0; k < 12; ++k){
      int e = j16 + 16 * k;
      float xn = (e < IDIM) ? (vals[k] - mu) * rstd * g1[e] + b1[e] : 0.f;
      xnbf[row * 192 + e] = f2bf(xn);
    }
  }
  __syncthreads();

  int w = t >> 6, l = t & 63, l15 = l & 15, q = l >> 4;

  { // dots(16x64) = xn(16x192) @ M(192x64); wave w does s-tile w
    f32x4 acc = (f32x4){0.f,0.f,0.f,0.f};
    const short* mtb = MT + (size_t)(b * NS + 16 * w + l15) * 192;
    #pragma unroll
    for (int ks = 0; ks < 6; ++ks){
      bf16x8 af = *(const bf16x8*)(xnbf + l15 * 192 + ks * 32 + q * 8);
      bf16x8 bf = *(const bf16x8*)(mtb + ks * 32 + q * 8);
      acc = __builtin_amdgcn_mfma_f32_16x16x32_bf16(af, bf, acc, 0, 0, 0);
    }
    const float scale = 0.025515518153991442f;      // 1536^-0.5
    #pragma unroll
    for (int r = 0; r < 4; ++r)
      dotsS[(q * 4 + r) * 68 + 16 * w + l15] = acc[r] * scale;
  }
  __syncthreads();

  { // softmax over 64 slots; write w (fp32 global) + wbf (bf16 LDS)
    int row = t >> 4, j16 = t & 15;
    float d0[4];
    float mx = -1e30f;
    #pragma unroll
    for (int j = 0; j < 4; ++j){ d0[j] = dotsS[row * 68 + j16 + 16 * j]; mx = fmaxf(mx, d0[j]); }
    #pragma unroll
    for (int m = 1; m < 16; m <<= 1) mx = fmaxf(mx, __shfl_xor(mx, m));
    float sum = 0.f;
    #pragma unroll
    for (int j = 0; j < 4; ++j){ d0[j] = __expf(d0[j] - mx); sum += d0[j]; }
    #pragma unroll
    for (int m = 1; m < 16; m <<= 1) sum += __shfl_xor(sum, m);
    float inv = 1.f / sum;
    float* wrow = outW + (size_t)(b * NI + i0 + row) * NS;
    #pragma unroll
    for (int j = 0; j < 4; ++j){
      float wv = d0[j] * inv;
      wrow[j16 + 16 * j] = wv;
      wbf[row * 80 + j16 + 16 * j] = f2bf(wv);
    }
  }
  __syncthreads();

  { // s = w @ slot (16 x 1536, K=64), stats from C-frags, LN2, store
    bf16x8 a0 = *(const bf16x8*)(wbf + l15 * 80 + q * 8);
    bf16x8 a1 = *(const bf16x8*)(wbf + l15 * 80 + 32 + q * 8);
    const short* stb = slotT + ((size_t)b * SDIM) * NS;
    f32x4 acc[24];
    float sum[4] = {0,0,0,0}, sq[4] = {0,0,0,0};
    #pragma unroll
    for (int ct = 0; ct < 24; ++ct){
      int c = w * 384 + ct * 16 + l15;
      const short* col = stb + (size_t)c * NS;
      bf16x8 bf0 = *(const bf16x8*)(col + q * 8);
      bf16x8 bf1 = *(const bf16x8*)(col + 32 + q * 8);
      f32x4 a = (f32x4){0.f,0.f,0.f,0.f};
      a = __builtin_amdgcn_mfma_f32_16x16x32_bf16(a0, bf0, a, 0, 0, 0);
      a = __builtin_amdgcn_mfma_f32_16x16x32_bf16(a1, bf1, a, 0, 0, 0);
      acc[ct] = a;
      #pragma unroll
      for (int r = 0; r < 4; ++r){ sum[r] += a[r]; sq[r] += a[r] * a[r]; }
    }
    #pragma unroll
    for (int m = 1; m < 16; m <<= 1){
      #pragma unroll
      for (int r = 0; r < 4; ++r){
        sum[r] += __shfl_xor(sum[r], m);
        sq[r]  += __shfl_xor(sq[r],  m);
      }
    }
    if (l15 == 0){
      #pragma unroll
      for (int r = 0; r < 4; ++r){
        stats[w][q * 4 + r][0] = sum[r];
        stats[w][q * 4 + r][1] = sq[r];
      }
    }
    __syncthreads();
    if (t < 16){
      float s0 = 0.f, s1 = 0.f;
      #pragma unroll
      for (int ww = 0; ww < 4; ++ww){ s0 += stats[ww][t][0]; s1 += stats[ww][t][1]; }
      float mu  = s0 * (1.f / SDIM);
      float var = s1 * (1.f / SDIM) - mu * mu;
      smu[t] = mu; srstd[t] = rsqrtf(var + 1e-5f);
    }
    __syncthreads();
    float mu[4], rs[4];
    #pragma unroll
    for (int r = 0; r < 4; ++r){ mu[r] = smu[q * 4 + r]; rs[r] = srstd[q * 4 + r]; }
    float* obase = outS + (size_t)(b * NI + i0) * SDIM;
    #pragma unroll
    for (int ct = 0; ct < 24; ++ct){
      int c = w * 384 + ct * 16 + l15;
      float g = g2[c], bb = b2[c];
      float* orow = obase + c;
      #pragma unroll
      for (int r = 0; r < 4; ++r){
        float v = (acc[ct][r] - mu[r]) * rs[r] * g + bb;
        orow[(size_t)(q * 4 + r) * SDIM] = v;
      }
    }
  }
}

extern "C" void kernel_launch(void* const* d_in, const int* in_sizes, int n_in,
                              void* d_out, int out_size, void* d_ws, size_t ws_size,
                              hipStream_t stream){
  const float* x    = (const float*)d_in[0];
  const float* slot = (const float*)d_in[1];
  const float* Wq   = (const float*)d_in[2];
  const float* Wk   = (const float*)d_in[3];
  const float* g1   = (const float*)d_in[4];
  const float* b1   = (const float*)d_in[5];
  const float* g2   = (const float*)d_in[6];
  const float* b2   = (const float*)d_in[7];
  float* outS = (float*)d_out;
  float* outW = outS + (size_t)NB * NI * SDIM;

  short* slot_bf = (short*)d_ws;                     // 786432 bf16
  short* slotT   = slot_bf + (size_t)NB * NS * SDIM; // 786432 bf16
  short* A_bf    = slotT + (size_t)NB * NS * SDIM;   // 192*1536 bf16
  short* MT      = A_bf + (size_t)192 * SDIM;        // 8*64*192 bf16   (~3.9 MB total)

  kA<<<(NB * NS * SDIM) / 256, 256, 0, stream>>>(slot, slot_bf, slotT);
  kB<<<96, 256, 0, stream>>>(Wq, Wk, A_bf);
  kC<<<32, 256, 0, stream>>>(A_bf, slot_bf, MT);
  kD<<<(NB * NI) / 16, 256, 0, stream>>>(x, slotT, MT, g1, b1, g2, b2, outS, outW);
}